// Round 3
// baseline (440.119 us; speedup 1.0000x reference)
//
#include <hip/hip_runtime.h>

typedef __attribute__((ext_vector_type(8))) short short8;
typedef __attribute__((ext_vector_type(4))) float f32x4;

__device__ __forceinline__ float b2f(unsigned short u) {
  union { unsigned u32; float f; } x; x.u32 = ((unsigned)u) << 16; return x.f;
}
__device__ __forceinline__ unsigned short f2bf(float f) {
  union { float f; unsigned u; } x; x.f = f;
  unsigned r = x.u + 0x7fffu + ((x.u >> 16) & 1u);
  return (unsigned short)(r >> 16);
}
__device__ __forceinline__ void async_load16(const void* g, void* l) {
  __builtin_amdgcn_global_load_lds(
      (__attribute__((address_space(1))) void*)(void*)(g),
      (__attribute__((address_space(3))) void*)(l), 16, 0, 0);
}

// ---- fp32 -> bf16 convert (weights), n4 = n/4 ----
__global__ __launch_bounds__(256) void cvt_k(const float* __restrict__ in,
                                             unsigned short* __restrict__ out, int n4) {
  int i = blockIdx.x * 256 + threadIdx.x;
  if (i < n4) {
    float4 v = ((const float4*)in)[i];
    unsigned short o[4] __attribute__((aligned(8)));
    o[0] = f2bf(v.x); o[1] = f2bf(v.y); o[2] = f2bf(v.z); o[3] = f2bf(v.w);
    ((int2*)out)[i] = *(int2*)o;
  }
}

// ---- GroupNorm: x[b][c][p] fp32 -> hin[b][p][c] bf16 (transposed) ----
__global__ __launch_bounds__(256) void groupnorm_k(
    const float* __restrict__ x, const float* __restrict__ gamma,
    const float* __restrict__ beta, unsigned short* __restrict__ hin) {
  const int b = blockIdx.x >> 5, g = blockIdx.x & 31;
  const float* xb = x + ((unsigned long long)b * 512ull + (unsigned long long)g * 16ull) * 1024ull;
  const int t = threadIdx.x;
  float s = 0.f, ss = 0.f;
  for (int i = t * 4; i < 16384; i += 1024) {
    float4 v = *(const float4*)(xb + i);
    s += v.x + v.y + v.z + v.w;
    ss += v.x * v.x + v.y * v.y + v.z * v.z + v.w * v.w;
  }
#pragma unroll
  for (int o = 32; o; o >>= 1) { s += __shfl_down(s, o); ss += __shfl_down(ss, o); }
  __shared__ float sred[8];
  if ((t & 63) == 0) { sred[t >> 6] = s; sred[4 + (t >> 6)] = ss; }
  __syncthreads();
  s = sred[0] + sred[1] + sred[2] + sred[3];
  ss = sred[4] + sred[5] + sred[6] + sred[7];
  const float mean = s * (1.f / 16384.f);
  const float rstd = rsqrtf(ss * (1.f / 16384.f) - mean * mean + 1e-5f);
  float ga[16], be[16];
#pragma unroll
  for (int c = 0; c < 16; ++c) {
    float gg = gamma[g * 16 + c] * rstd;
    ga[c] = gg;
    be[c] = beta[g * 16 + c] - mean * gg;
  }
  for (int p = t; p < 1024; p += 256) {
    unsigned short ov[16] __attribute__((aligned(16)));
#pragma unroll
    for (int c = 0; c < 16; ++c)
      ov[c] = f2bf(xb[(unsigned long long)c * 1024ull + p] * ga[c] + be[c]);
    unsigned short* dst = hin + ((unsigned long long)b * 1024ull + p) * 512ull + g * 16;
    *(int4*)dst = *(int4*)ov;
    *(int4*)(dst + 8) = *(int4*)(ov + 8);
  }
}

// ---- GEMM: C[m][n] = sum_k A[m][k]*B[n][k], A/B bf16 K-contiguous ----
// MODE 0: QKV epilogue (fp32 bias, scale q/k, V stored transposed [c][p])
// MODE 1: scores -> S bf16
// MODE 2: PV -> H[b][i][c] bf16
// MODE 3: proj -> fout = x + bias + acc (fp32)
template <int MODE>
__global__ __launch_bounds__(256) void gemm_k(
    const unsigned short* __restrict__ A, unsigned long long sA, int lda,
    const unsigned short* __restrict__ B, unsigned long long sB, int ldb,
    const float* __restrict__ bias, const float* __restrict__ xres,
    unsigned short* __restrict__ out0, unsigned short* __restrict__ out1,
    unsigned short* __restrict__ out2, float* __restrict__ fout,
    float scale, int K) {
  __shared__ unsigned short As[128 * 32];
  __shared__ unsigned short Bs[128 * 32];
  const int tid = threadIdx.x;
  const int wave = tid >> 6, lane = tid & 63;
  const int b = blockIdx.z;
  const int m0 = blockIdx.y * 128, n0 = blockIdx.x * 128;
  const int wm = (wave & 1) * 64, wn = (wave >> 1) * 64;
  const unsigned short* Ab = A + (unsigned long long)b * sA + (unsigned long long)m0 * lda;
  const unsigned short* Bb = B + (unsigned long long)b * sB + (unsigned long long)n0 * ldb;

  f32x4 acc[4][4];
#pragma unroll
  for (int i = 0; i < 4; ++i)
#pragma unroll
    for (int j = 0; j < 4; ++j)
#pragma unroll
      for (int r = 0; r < 4; ++r) acc[i][j][r] = 0.f;

  const int lrow = lane & 15;
  const int lk = lane >> 4;
  const int srow = lane >> 2;       // staging row within 16-row chunk
  const int scol = (lane & 3) * 8;  // staging element offset (16B)

  for (int kt = 0; kt < K; kt += 32) {
    {
      const unsigned short* ga = Ab + kt + (unsigned long long)(wave * 16 + srow) * lda + scol;
      async_load16(ga, (void*)(As + wave * 512));
      async_load16(ga + 64ull * (unsigned long long)lda, (void*)(As + (wave + 4) * 512));
      const unsigned short* gb = Bb + kt + (unsigned long long)(wave * 16 + srow) * ldb + scol;
      async_load16(gb, (void*)(Bs + wave * 512));
      async_load16(gb + 64ull * (unsigned long long)ldb, (void*)(Bs + (wave + 4) * 512));
    }
    __syncthreads();
    short8 af[4], bfr[4];
#pragma unroll
    for (int i = 0; i < 4; ++i) {
      af[i] = *(const short8*)(As + (wm + i * 16 + lrow) * 32 + lk * 8);
      bfr[i] = *(const short8*)(Bs + (wn + i * 16 + lrow) * 32 + lk * 8);
    }
#pragma unroll
    for (int mi = 0; mi < 4; ++mi)
#pragma unroll
      for (int ni = 0; ni < 4; ++ni)
        acc[mi][ni] = __builtin_amdgcn_mfma_f32_16x16x32_bf16(af[mi], bfr[ni], acc[mi][ni], 0, 0, 0);
    __syncthreads();
  }

  const int r0 = lk * 4;   // C/D: row = (lane>>4)*4 + reg
  const int cn = lrow;     // C/D: col = lane&15

  if (MODE == 0) {
    const int which = n0 >> 9;  // 0=Q 1=K 2=V
#pragma unroll
    for (int ni = 0; ni < 4; ++ni) {
      const int o = n0 + wn + ni * 16 + cn;
      const float bi = bias[o];
      const int oin = o & 511;
      if (which < 2) {
        unsigned short* dst = (which == 0 ? out0 : out1) + (unsigned long long)b * 524288ull;
#pragma unroll
        for (int mi = 0; mi < 4; ++mi) {
          const int pbase = m0 + wm + mi * 16 + r0;
#pragma unroll
          for (int r = 0; r < 4; ++r)
            dst[(unsigned long long)(pbase + r) * 512ull + oin] = f2bf((acc[mi][ni][r] + bi) * scale);
        }
      } else {
        unsigned short* dst = out2 + (unsigned long long)b * 524288ull + (unsigned long long)oin * 1024ull;
#pragma unroll
        for (int mi = 0; mi < 4; ++mi) {
          const int pbase = m0 + wm + mi * 16 + r0;
          unsigned short h4[4] __attribute__((aligned(8)));
#pragma unroll
          for (int r = 0; r < 4; ++r) h4[r] = f2bf(acc[mi][ni][r] + bi);
          *(int2*)(dst + pbase) = *(int2*)h4;
        }
      }
    }
  } else if (MODE == 1) {
    unsigned short* dst = out0 + (unsigned long long)b * 1048576ull;
#pragma unroll
    for (int mi = 0; mi < 4; ++mi) {
      const int ib = m0 + wm + mi * 16 + r0;
#pragma unroll
      for (int ni = 0; ni < 4; ++ni) {
        const int j = n0 + wn + ni * 16 + cn;
#pragma unroll
        for (int r = 0; r < 4; ++r)
          dst[(unsigned long long)(ib + r) * 1024ull + j] = f2bf(acc[mi][ni][r]);
      }
    }
  } else if (MODE == 2) {
    unsigned short* dst = out0 + (unsigned long long)b * 524288ull;
#pragma unroll
    for (int mi = 0; mi < 4; ++mi) {
      const int ib = m0 + wm + mi * 16 + r0;
#pragma unroll
      for (int ni = 0; ni < 4; ++ni) {
        const int c = n0 + wn + ni * 16 + cn;
#pragma unroll
        for (int r = 0; r < 4; ++r)
          dst[(unsigned long long)(ib + r) * 512ull + c] = f2bf(acc[mi][ni][r]);
      }
    }
  } else {  // MODE 3: fp32 out = acc + bias + x
    float* dst = fout + (unsigned long long)b * 524288ull;
    const float* xr = xres + (unsigned long long)b * 524288ull;
#pragma unroll
    for (int mi = 0; mi < 4; ++mi) {
      const int ob = m0 + wm + mi * 16 + r0;
#pragma unroll
      for (int r = 0; r < 4; ++r) {
        const int o = ob + r;
        const float bi = bias[o];
#pragma unroll
        for (int ni = 0; ni < 4; ++ni) {
          const int p = n0 + wn + ni * 16 + cn;
          const unsigned long long idx = (unsigned long long)o * 1024ull + p;
          dst[idx] = acc[mi][ni][r] + bi + xr[idx];
        }
      }
    }
  }
}

// ---- segmented softmax: 32 independent softmaxes of 32 elements per 1024-row ----
// Reference does softmax over last axis (kw) only; kp = kh*32+kw is contiguous in
// chunks of 32. Each thread holds 4 contiguous elems; a chunk = 8 lanes; reduce
// via __shfl_xor(1,2,4) in-register. No LDS, no barriers.
__global__ __launch_bounds__(256) void softmax_k(unsigned short* __restrict__ S) {
  unsigned short* rp = S + (unsigned long long)blockIdx.x * 1024ull;
  const int t = threadIdx.x;
  unsigned short v4[4] __attribute__((aligned(8)));
  *(int2*)v4 = ((const int2*)rp)[t];
  float v0 = b2f(v4[0]), v1 = b2f(v4[1]), v2 = b2f(v4[2]), v3 = b2f(v4[3]);
  float m = fmaxf(fmaxf(v0, v1), fmaxf(v2, v3));
  m = fmaxf(m, __shfl_xor(m, 1));
  m = fmaxf(m, __shfl_xor(m, 2));
  m = fmaxf(m, __shfl_xor(m, 4));
  float e0 = __expf(v0 - m), e1 = __expf(v1 - m), e2 = __expf(v2 - m), e3 = __expf(v3 - m);
  float sum = e0 + e1 + e2 + e3;
  sum += __shfl_xor(sum, 1);
  sum += __shfl_xor(sum, 2);
  sum += __shfl_xor(sum, 4);
  const float inv = 1.f / sum;
  v4[0] = f2bf(e0 * inv); v4[1] = f2bf(e1 * inv); v4[2] = f2bf(e2 * inv); v4[3] = f2bf(e3 * inv);
  ((int2*)rp)[t] = *(int2*)v4;
}

extern "C" void kernel_launch(void* const* d_in, const int* in_sizes, int n_in,
                              void* d_out, int out_size, void* d_ws, size_t ws_size,
                              hipStream_t stream) {
  const float* x     = (const float*)d_in[0];
  const float* gamma = (const float*)d_in[1];
  const float* beta  = (const float*)d_in[2];
  const float* qkvw  = (const float*)d_in[3];
  const float* qkvb  = (const float*)d_in[4];
  const float* projw = (const float*)d_in[5];
  const float* projb = (const float*)d_in[6];
  float* out = (float*)d_out;
  char* ws = (char*)d_ws;

  unsigned short* Hin = (unsigned short*)(ws);                        // 32 MB [b][p][c]
  unsigned short* Q   = (unsigned short*)(ws + 1ull * 33554432ull);   // 32 MB [b][p][c]
  unsigned short* Kb  = (unsigned short*)(ws + 2ull * 33554432ull);   // 32 MB [b][p][c]
  unsigned short* V   = (unsigned short*)(ws + 3ull * 33554432ull);   // 32 MB [b][c][p]
  unsigned short* S   = (unsigned short*)(ws + 4ull * 33554432ull);   // 64 MB [b][i][j]
  unsigned short* Wq  = (unsigned short*)(ws + 6ull * 33554432ull);   // 1.5 MB [1536][512]
  unsigned short* Wp  = (unsigned short*)(ws + 6ull * 33554432ull + 2ull * 1048576ull); // 0.5 MB
  unsigned short* H   = Hin;  // reuse: Hin dead after QKV GEMM

  const float SCALE = 0.21022410381342864f;  // 512^-0.25
  dim3 blk(256);
  const float* nzf = nullptr;
  unsigned short* nzo = nullptr;
  float* nzfo = nullptr;

  hipLaunchKernelGGL(cvt_k, dim3(768), blk, 0, stream, qkvw, Wq, 196608);
  hipLaunchKernelGGL(cvt_k, dim3(256), blk, 0, stream, projw, Wp, 65536);
  hipLaunchKernelGGL(groupnorm_k, dim3(1024), blk, 0, stream, x, gamma, beta, Hin);
  hipLaunchKernelGGL((gemm_k<0>), dim3(12, 8, 32), blk, 0, stream,
                     Hin, 524288ull, 512, Wq, 0ull, 512, qkvb, nzf, Q, Kb, V, nzfo, SCALE, 512);
  hipLaunchKernelGGL((gemm_k<1>), dim3(8, 8, 32), blk, 0, stream,
                     Q, 524288ull, 512, Kb, 524288ull, 512, nzf, nzf, S, nzo, nzo, nzfo, 0.f, 512);
  hipLaunchKernelGGL(softmax_k, dim3(32768), blk, 0, stream, S);
  hipLaunchKernelGGL((gemm_k<2>), dim3(4, 8, 32), blk, 0, stream,
                     S, 1048576ull, 1024, V, 524288ull, 1024, nzf, nzf, H, nzo, nzo, nzfo, 0.f, 1024);
  hipLaunchKernelGGL((gemm_k<3>), dim3(8, 4, 32), blk, 0, stream,
                     Wp, 0ull, 512, H, 524288ull, 512, projb, x, nzo, nzo, nzo, out, 0.f, 512);
}

// Round 4
// 403.996 us; speedup vs baseline: 1.0894x; 1.0894x over previous
//
#include <hip/hip_runtime.h>

typedef __attribute__((ext_vector_type(8))) short short8;
typedef __attribute__((ext_vector_type(4))) float f32x4;

__device__ __forceinline__ float b2f(unsigned short u) {
  union { unsigned u32; float f; } x; x.u32 = ((unsigned)u) << 16; return x.f;
}
__device__ __forceinline__ unsigned short f2bf(float f) {
  union { float f; unsigned u; } x; x.f = f;
  unsigned r = x.u + 0x7fffu + ((x.u >> 16) & 1u);
  return (unsigned short)(r >> 16);
}
__device__ __forceinline__ void async_load16(const void* g, void* l) {
  __builtin_amdgcn_global_load_lds(
      (__attribute__((address_space(1))) void*)(void*)(g),
      (__attribute__((address_space(3))) void*)(l), 16, 0, 0);
}

// ---- fp32 -> bf16 convert (weights), n4 = n/4 ----
__global__ __launch_bounds__(256) void cvt_k(const float* __restrict__ in,
                                             unsigned short* __restrict__ out, int n4) {
  int i = blockIdx.x * 256 + threadIdx.x;
  if (i < n4) {
    float4 v = ((const float4*)in)[i];
    unsigned short o[4] __attribute__((aligned(8)));
    o[0] = f2bf(v.x); o[1] = f2bf(v.y); o[2] = f2bf(v.z); o[3] = f2bf(v.w);
    ((int2*)out)[i] = *(int2*)o;
  }
}

// ---- GroupNorm single-pass: x[b][c][p] fp32 -> hin[b][p][c] bf16 (transposed) ----
// x tile (16 ch x 1024 px) cached in registers (16 float4/thread) -> one HBM read.
__global__ __launch_bounds__(256) void groupnorm_k(
    const float* __restrict__ x, const float* __restrict__ gamma,
    const float* __restrict__ beta, unsigned short* __restrict__ hin) {
  const int b = blockIdx.x >> 5, g = blockIdx.x & 31;
  const float* xb = x + ((unsigned long long)b * 512ull + (unsigned long long)g * 16ull) * 1024ull;
  const int t = threadIdx.x;
  float4 xr[16];
  float s = 0.f, ss = 0.f;
#pragma unroll
  for (int c = 0; c < 16; ++c) {
    xr[c] = *(const float4*)(xb + c * 1024 + t * 4);
    s += xr[c].x + xr[c].y + xr[c].z + xr[c].w;
    ss += xr[c].x * xr[c].x + xr[c].y * xr[c].y + xr[c].z * xr[c].z + xr[c].w * xr[c].w;
  }
#pragma unroll
  for (int o = 32; o; o >>= 1) { s += __shfl_down(s, o); ss += __shfl_down(ss, o); }
  __shared__ float sred[8];
  if ((t & 63) == 0) { sred[t >> 6] = s; sred[4 + (t >> 6)] = ss; }
  __syncthreads();
  s = sred[0] + sred[1] + sred[2] + sred[3];
  ss = sred[4] + sred[5] + sred[6] + sred[7];
  const float mean = s * (1.f / 16384.f);
  const float rstd = rsqrtf(ss * (1.f / 16384.f) - mean * mean + 1e-5f);
  float ga[16], be[16];
#pragma unroll
  for (int c = 0; c < 16; ++c) {
    float gg = gamma[g * 16 + c] * rstd;
    ga[c] = gg;
    be[c] = beta[g * 16 + c] - mean * gg;
  }
#pragma unroll
  for (int p4 = 0; p4 < 4; ++p4) {
    unsigned short ov[16] __attribute__((aligned(16)));
#pragma unroll
    for (int c = 0; c < 16; ++c)
      ov[c] = f2bf(((const float*)&xr[c])[p4] * ga[c] + be[c]);
    unsigned short* dst = hin + ((unsigned long long)b * 1024ull + t * 4 + p4) * 512ull + g * 16;
    *(int4*)dst = *(int4*)ov;
    *(int4*)(dst + 8) = *(int4*)(ov + 8);
  }
}

// ---- GEMM: C[m][n] = sum_k A[m][k]*B[n][k], A/B bf16 K-contiguous ----
// LDS XOR-swizzled (16B col-block ^ row bits 1-2) -> conflict-free ds_read_b128;
// swizzle applied at staging-source addresses (global_load_lds lane map is fixed).
// MODE 0: QKV epilogue (bias, scale q/k, V transposed [c][p]); XCD-aware block swizzle.
// MODE 1: scores + fused segmented softmax (32-wide chunks) -> P bf16
// MODE 2: PV -> H[b][i][c] bf16
// MODE 3: proj -> fout = x + bias + acc (fp32)
template <int MODE>
__global__ __launch_bounds__(256) void gemm_k(
    const unsigned short* __restrict__ A, unsigned long long sA, int lda,
    const unsigned short* __restrict__ B, unsigned long long sB, int ldb,
    const float* __restrict__ bias, const float* __restrict__ xres,
    unsigned short* __restrict__ out0, unsigned short* __restrict__ out1,
    unsigned short* __restrict__ out2, float* __restrict__ fout,
    float scale, int K) {
  __shared__ unsigned short As[128 * 32];
  __shared__ unsigned short Bs[128 * 32];
  const int tid = threadIdx.x;
  const int wave = tid >> 6, lane = tid & 63;

  int n_t, m_t, b;
  if (MODE == 0) {
    // XCD swizzle: all 12 n-tiles of one (m,b) share L%8 -> same XCD -> A-tile
    // fetched once per XCD instead of ~8x. (gridDim.y==8 for QKV)
    const int L = blockIdx.x + gridDim.x * (blockIdx.y + gridDim.y * blockIdx.z);
    const int r8 = L & 7, q = L >> 3;
    n_t = q % 12;
    const int mb = (q / 12) * 8 + r8;
    m_t = mb & 7;
    b = mb >> 3;
  } else {
    n_t = blockIdx.x; m_t = blockIdx.y; b = blockIdx.z;
  }
  const int m0 = m_t * 128, n0 = n_t * 128;
  const int wm = (wave & 1) * 64, wn = (wave >> 1) * 64;
  const unsigned short* Ab = A + (unsigned long long)b * sA + (unsigned long long)m0 * lda;
  const unsigned short* Bb = B + (unsigned long long)b * sB + (unsigned long long)n0 * ldb;

  f32x4 acc[4][4];
#pragma unroll
  for (int i = 0; i < 4; ++i)
#pragma unroll
    for (int j = 0; j < 4; ++j)
#pragma unroll
      for (int r = 0; r < 4; ++r) acc[i][j][r] = 0.f;

  const int lrow = lane & 15;
  const int lk = lane >> 4;
  const int srow = lane >> 2;  // staging row within 16-row chunk
  // staging source col-block: lane's LDS slot (lane&3) holds swizzled block
  const int scol = (((lane & 3) ^ ((lane >> 3) & 3)) << 3);
  const int swz = (lrow >> 1) & 3;  // fragment-read swizzle (row bits 1-2)

  for (int kt = 0; kt < K; kt += 32) {
    {
      const unsigned short* ga = Ab + kt + (unsigned long long)(wave * 16 + srow) * lda + scol;
      async_load16(ga, (void*)(As + wave * 512));
      async_load16(ga + 64ull * (unsigned long long)lda, (void*)(As + (wave + 4) * 512));
      const unsigned short* gb = Bb + kt + (unsigned long long)(wave * 16 + srow) * ldb + scol;
      async_load16(gb, (void*)(Bs + wave * 512));
      async_load16(gb + 64ull * (unsigned long long)ldb, (void*)(Bs + (wave + 4) * 512));
    }
    __syncthreads();
    short8 af[4], bfr[4];
#pragma unroll
    for (int i = 0; i < 4; ++i) {
      af[i] = *(const short8*)(As + (wm + i * 16 + lrow) * 32 + ((lk ^ swz) << 3));
      bfr[i] = *(const short8*)(Bs + (wn + i * 16 + lrow) * 32 + ((lk ^ swz) << 3));
    }
#pragma unroll
    for (int mi = 0; mi < 4; ++mi)
#pragma unroll
      for (int ni = 0; ni < 4; ++ni)
        acc[mi][ni] = __builtin_amdgcn_mfma_f32_16x16x32_bf16(af[mi], bfr[ni], acc[mi][ni], 0, 0, 0);
    __syncthreads();
  }

  const int r0 = lk * 4;  // C/D: row = (lane>>4)*4 + reg
  const int cn = lrow;    // C/D: col = lane&15

  if (MODE == 0) {
    const int which = n0 >> 9;  // 0=Q 1=K 2=V
#pragma unroll
    for (int ni = 0; ni < 4; ++ni) {
      const int o = n0 + wn + ni * 16 + cn;
      const float bi = bias[o];
      const int oin = o & 511;
      if (which < 2) {
        unsigned short* dst = (which == 0 ? out0 : out1) + (unsigned long long)b * 524288ull;
#pragma unroll
        for (int mi = 0; mi < 4; ++mi) {
          const int pbase = m0 + wm + mi * 16 + r0;
#pragma unroll
          for (int r = 0; r < 4; ++r)
            dst[(unsigned long long)(pbase + r) * 512ull + oin] = f2bf((acc[mi][ni][r] + bi) * scale);
        }
      } else {
        unsigned short* dst = out2 + (unsigned long long)b * 524288ull + (unsigned long long)oin * 1024ull;
#pragma unroll
        for (int mi = 0; mi < 4; ++mi) {
          const int pbase = m0 + wm + mi * 16 + r0;
          unsigned short h4[4] __attribute__((aligned(8)));
#pragma unroll
          for (int r = 0; r < 4; ++r) h4[r] = f2bf(acc[mi][ni][r] + bi);
          *(int2*)(dst + pbase) = *(int2*)h4;
        }
      }
    }
  } else if (MODE == 1) {
    // fused segmented softmax: chunk of 32 j = ni-pair {2p,2p+1} x 16 lanes of a quad
    unsigned short* dst = out0 + (unsigned long long)b * 1048576ull;
#pragma unroll
    for (int mi = 0; mi < 4; ++mi) {
#pragma unroll
      for (int pr = 0; pr < 2; ++pr) {
#pragma unroll
        for (int r = 0; r < 4; ++r) {
          float a0 = acc[mi][pr * 2][r], a1 = acc[mi][pr * 2 + 1][r];
          float m = fmaxf(a0, a1);
          m = fmaxf(m, __shfl_xor(m, 1));
          m = fmaxf(m, __shfl_xor(m, 2));
          m = fmaxf(m, __shfl_xor(m, 4));
          m = fmaxf(m, __shfl_xor(m, 8));
          float e0 = __expf(a0 - m), e1 = __expf(a1 - m);
          float sm = e0 + e1;
          sm += __shfl_xor(sm, 1);
          sm += __shfl_xor(sm, 2);
          sm += __shfl_xor(sm, 4);
          sm += __shfl_xor(sm, 8);
          const float inv = 1.f / sm;
          const unsigned long long ib = (unsigned long long)(m0 + wm + mi * 16 + r0 + r) * 1024ull;
          const int j0 = n0 + wn + pr * 32 + cn;
          dst[ib + j0] = f2bf(e0 * inv);
          dst[ib + j0 + 16] = f2bf(e1 * inv);
        }
      }
    }
  } else if (MODE == 2) {
    unsigned short* dst = out0 + (unsigned long long)b * 524288ull;
#pragma unroll
    for (int mi = 0; mi < 4; ++mi) {
      const int ib = m0 + wm + mi * 16 + r0;
#pragma unroll
      for (int ni = 0; ni < 4; ++ni) {
        const int c = n0 + wn + ni * 16 + cn;
#pragma unroll
        for (int r = 0; r < 4; ++r)
          dst[(unsigned long long)(ib + r) * 512ull + c] = f2bf(acc[mi][ni][r]);
      }
    }
  } else {  // MODE 3: fp32 out = acc + bias + x
    float* dst = fout + (unsigned long long)b * 524288ull;
    const float* xr = xres + (unsigned long long)b * 524288ull;
#pragma unroll
    for (int mi = 0; mi < 4; ++mi) {
      const int ob = m0 + wm + mi * 16 + r0;
#pragma unroll
      for (int r = 0; r < 4; ++r) {
        const int o = ob + r;
        const float bi = bias[o];
#pragma unroll
        for (int ni = 0; ni < 4; ++ni) {
          const int p = n0 + wn + ni * 16 + cn;
          const unsigned long long idx = (unsigned long long)o * 1024ull + p;
          dst[idx] = acc[mi][ni][r] + bi + xr[idx];
        }
      }
    }
  }
}

extern "C" void kernel_launch(void* const* d_in, const int* in_sizes, int n_in,
                              void* d_out, int out_size, void* d_ws, size_t ws_size,
                              hipStream_t stream) {
  const float* x     = (const float*)d_in[0];
  const float* gamma = (const float*)d_in[1];
  const float* beta  = (const float*)d_in[2];
  const float* qkvw  = (const float*)d_in[3];
  const float* qkvb  = (const float*)d_in[4];
  const float* projw = (const float*)d_in[5];
  const float* projb = (const float*)d_in[6];
  float* out = (float*)d_out;
  char* ws = (char*)d_ws;

  unsigned short* Hin = (unsigned short*)(ws);                        // 32 MB [b][p][c]
  unsigned short* Q   = (unsigned short*)(ws + 1ull * 33554432ull);   // 32 MB [b][p][c]
  unsigned short* Kb  = (unsigned short*)(ws + 2ull * 33554432ull);   // 32 MB [b][p][c]
  unsigned short* V   = (unsigned short*)(ws + 3ull * 33554432ull);   // 32 MB [b][c][p]
  unsigned short* S   = (unsigned short*)(ws + 4ull * 33554432ull);   // 64 MB [b][i][j] (P after fused softmax)
  unsigned short* Wq  = (unsigned short*)(ws + 6ull * 33554432ull);   // 1.5 MB [1536][512]
  unsigned short* Wp  = (unsigned short*)(ws + 6ull * 33554432ull + 2ull * 1048576ull); // 0.5 MB
  unsigned short* H   = Hin;  // reuse: Hin dead after QKV GEMM

  const float SCALE = 0.21022410381342864f;  // 512^-0.25
  dim3 blk(256);
  const float* nzf = nullptr;
  unsigned short* nzo = nullptr;
  float* nzfo = nullptr;

  hipLaunchKernelGGL(cvt_k, dim3(768), blk, 0, stream, qkvw, Wq, 196608);
  hipLaunchKernelGGL(cvt_k, dim3(256), blk, 0, stream, projw, Wp, 65536);
  hipLaunchKernelGGL(groupnorm_k, dim3(1024), blk, 0, stream, x, gamma, beta, Hin);
  hipLaunchKernelGGL((gemm_k<0>), dim3(12, 8, 32), blk, 0, stream,
                     Hin, 524288ull, 512, Wq, 0ull, 512, qkvb, nzf, Q, Kb, V, nzfo, SCALE, 512);
  hipLaunchKernelGGL((gemm_k<1>), dim3(8, 8, 32), blk, 0, stream,
                     Q, 524288ull, 512, Kb, 524288ull, 512, nzf, nzf, S, nzo, nzo, nzfo, 0.f, 512);
  hipLaunchKernelGGL((gemm_k<2>), dim3(4, 8, 32), blk, 0, stream,
                     S, 1048576ull, 1024, V, 524288ull, 1024, nzf, nzf, H, nzo, nzo, nzfo, 0.f, 1024);
  hipLaunchKernelGGL((gemm_k<3>), dim3(8, 4, 32), blk, 0, stream,
                     Wp, 0ull, 512, H, 524288ull, 512, projb, x, nzo, nzo, nzo, out, 0.f, 512);
}

// Round 5
// 375.405 us; speedup vs baseline: 1.1724x; 1.0762x over previous
//
#include <hip/hip_runtime.h>

typedef __attribute__((ext_vector_type(8))) short short8;
typedef __attribute__((ext_vector_type(4))) float f32x4;

__device__ __forceinline__ float b2f(unsigned short u) {
  union { unsigned u32; float f; } x; x.u32 = ((unsigned)u) << 16; return x.f;
}
__device__ __forceinline__ unsigned short f2bf(float f) {
  union { float f; unsigned u; } x; x.f = f;
  unsigned r = x.u + 0x7fffu + ((x.u >> 16) & 1u);
  return (unsigned short)(r >> 16);
}
__device__ __forceinline__ void async_load16(const void* g, void* l) {
  __builtin_amdgcn_global_load_lds(
      (__attribute__((address_space(1))) void*)(void*)(g),
      (__attribute__((address_space(3))) void*)(l), 16, 0, 0);
}

// ---- fp32 -> bf16 convert (weights), n4 = n/4 ----
__global__ __launch_bounds__(256) void cvt_k(const float* __restrict__ in,
                                             unsigned short* __restrict__ out, int n4) {
  int i = blockIdx.x * 256 + threadIdx.x;
  if (i < n4) {
    float4 v = ((const float4*)in)[i];
    unsigned short o[4] __attribute__((aligned(8)));
    o[0] = f2bf(v.x); o[1] = f2bf(v.y); o[2] = f2bf(v.z); o[3] = f2bf(v.w);
    ((int2*)out)[i] = *(int2*)o;
  }
}

// ---- GroupNorm single-pass: x[b][c][p] fp32 -> hin[b][p][c] bf16 (transposed) ----
__global__ __launch_bounds__(256) void groupnorm_k(
    const float* __restrict__ x, const float* __restrict__ gamma,
    const float* __restrict__ beta, unsigned short* __restrict__ hin) {
  const int b = blockIdx.x >> 5, g = blockIdx.x & 31;
  const float* xb = x + ((unsigned long long)b * 512ull + (unsigned long long)g * 16ull) * 1024ull;
  const int t = threadIdx.x;
  float4 xr[16];
  float s = 0.f, ss = 0.f;
#pragma unroll
  for (int c = 0; c < 16; ++c) {
    xr[c] = *(const float4*)(xb + c * 1024 + t * 4);
    s += xr[c].x + xr[c].y + xr[c].z + xr[c].w;
    ss += xr[c].x * xr[c].x + xr[c].y * xr[c].y + xr[c].z * xr[c].z + xr[c].w * xr[c].w;
  }
#pragma unroll
  for (int o = 32; o; o >>= 1) { s += __shfl_down(s, o); ss += __shfl_down(ss, o); }
  __shared__ float sred[8];
  if ((t & 63) == 0) { sred[t >> 6] = s; sred[4 + (t >> 6)] = ss; }
  __syncthreads();
  s = sred[0] + sred[1] + sred[2] + sred[3];
  ss = sred[4] + sred[5] + sred[6] + sred[7];
  const float mean = s * (1.f / 16384.f);
  const float rstd = rsqrtf(ss * (1.f / 16384.f) - mean * mean + 1e-5f);
  float ga[16], be[16];
#pragma unroll
  for (int c = 0; c < 16; ++c) {
    float gg = gamma[g * 16 + c] * rstd;
    ga[c] = gg;
    be[c] = beta[g * 16 + c] - mean * gg;
  }
#pragma unroll
  for (int p4 = 0; p4 < 4; ++p4) {
    unsigned short ov[16] __attribute__((aligned(16)));
#pragma unroll
    for (int c = 0; c < 16; ++c)
      ov[c] = f2bf(((const float*)&xr[c])[p4] * ga[c] + be[c]);
    unsigned short* dst = hin + ((unsigned long long)b * 1024ull + t * 4 + p4) * 512ull + g * 16;
    *(int4*)dst = *(int4*)ov;
    *(int4*)(dst + 8) = *(int4*)(ov + 8);
  }
}

// ---- GEMM: C[m][n] = sum_k A[m][k]*B[n][k], A/B bf16 K-contiguous ----
// LDS XOR-swizzle on 16B col-blocks -> conflict-free ds_read_b128.
// MODE 0: QKV (A=Hin, B=W). Epilogue: bias, scale q/k, V transposed [c][p]. XCD swizzle.
// MODE 1: S^T (A=K, B=Q) + segmented softmax (j on row axis -> in-register reduce)
//         + LDS transpose -> P[i][j] coalesced stores. XCD swizzle.
// MODE 2: PV -> H[b][i][c] bf16. XCD swizzle.
// MODE 3: proj -> fout = x + bias + acc (fp32)
template <int MODE>
__global__ __launch_bounds__(256) void gemm_k(
    const unsigned short* __restrict__ A, unsigned long long sA, int lda,
    const unsigned short* __restrict__ B, unsigned long long sB, int ldb,
    const float* __restrict__ bias, const float* __restrict__ xres,
    unsigned short* __restrict__ out0, unsigned short* __restrict__ out1,
    unsigned short* __restrict__ out2, float* __restrict__ fout,
    float scale, int K) {
  // LDS: staging As/Bs (16 KB) unioned with MODE1's 128x136 transpose tile (34 KB)
  constexpr int SMEM_SHORTS = (MODE == 1) ? (128 * 136) : 8192;
  __shared__ unsigned short smem[SMEM_SHORTS];
  unsigned short* As = smem;
  unsigned short* Bs = smem + 4096;
  const int tid = threadIdx.x;
  const int wave = tid >> 6, lane = tid & 63;

  int n_t, m_t, b;
  if (MODE == 0) {
    const int L = blockIdx.x + gridDim.x * (blockIdx.y + gridDim.y * blockIdx.z);
    const int r8 = L & 7, q = L >> 3;
    n_t = q % 12;
    const int mb = (q / 12) * 8 + r8;
    m_t = mb & 7;
    b = mb >> 3;
  } else if (MODE == 1) {
    // 2048 blocks: xcd slice = L&7 owns batches [slice*4, slice*4+4); Q+K of a
    // batch (2 MB) fits the 4 MB XCD L2.
    const int L = blockIdx.x + gridDim.x * (blockIdx.y + gridDim.y * blockIdx.z);
    const int slice = L & 7, t = L >> 3;
    b = slice * 4 + (t >> 6);
    const int rem = t & 63;
    m_t = rem >> 3;
    n_t = rem & 7;
  } else if (MODE == 2) {
    // 1024 blocks: per-batch working set P-slice + V = 3 MB
    const int L = blockIdx.x + gridDim.x * (blockIdx.y + gridDim.y * blockIdx.z);
    const int slice = L & 7, t = L >> 3;
    b = slice * 4 + (t >> 5);
    const int rem = t & 31;
    m_t = rem >> 2;
    n_t = rem & 3;
  } else {
    n_t = blockIdx.x; m_t = blockIdx.y; b = blockIdx.z;
  }
  const int m0 = m_t * 128, n0 = n_t * 128;
  const int wm = (wave & 1) * 64, wn = (wave >> 1) * 64;
  const unsigned short* Ab = A + (unsigned long long)b * sA + (unsigned long long)m0 * lda;
  const unsigned short* Bb = B + (unsigned long long)b * sB + (unsigned long long)n0 * ldb;

  f32x4 acc[4][4];
#pragma unroll
  for (int i = 0; i < 4; ++i)
#pragma unroll
    for (int j = 0; j < 4; ++j)
#pragma unroll
      for (int r = 0; r < 4; ++r) acc[i][j][r] = 0.f;

  const int lrow = lane & 15;
  const int lk = lane >> 4;
  const int srow = lane >> 2;
  const int scol = (((lane & 3) ^ ((lane >> 3) & 3)) << 3);
  const int swz = (lrow >> 1) & 3;

  for (int kt = 0; kt < K; kt += 32) {
    {
      const unsigned short* ga = Ab + kt + (unsigned long long)(wave * 16 + srow) * lda + scol;
      async_load16(ga, (void*)(As + wave * 512));
      async_load16(ga + 64ull * (unsigned long long)lda, (void*)(As + (wave + 4) * 512));
      const unsigned short* gb = Bb + kt + (unsigned long long)(wave * 16 + srow) * ldb + scol;
      async_load16(gb, (void*)(Bs + wave * 512));
      async_load16(gb + 64ull * (unsigned long long)ldb, (void*)(Bs + (wave + 4) * 512));
    }
    __syncthreads();
    short8 af[4], bfr[4];
#pragma unroll
    for (int i = 0; i < 4; ++i) {
      af[i] = *(const short8*)(As + (wm + i * 16 + lrow) * 32 + ((lk ^ swz) << 3));
      bfr[i] = *(const short8*)(Bs + (wn + i * 16 + lrow) * 32 + ((lk ^ swz) << 3));
    }
#pragma unroll
    for (int mi = 0; mi < 4; ++mi)
#pragma unroll
      for (int ni = 0; ni < 4; ++ni)
        acc[mi][ni] = __builtin_amdgcn_mfma_f32_16x16x32_bf16(af[mi], bfr[ni], acc[mi][ni], 0, 0, 0);
    __syncthreads();
  }

  const int r0 = lk * 4;  // C/D: row = (lane>>4)*4 + reg
  const int cn = lrow;    // C/D: col = lane&15

  if (MODE == 0) {
    const int which = n0 >> 9;  // 0=Q 1=K 2=V
#pragma unroll
    for (int ni = 0; ni < 4; ++ni) {
      const int o = n0 + wn + ni * 16 + cn;
      const float bi = bias[o];
      const int oin = o & 511;
      if (which < 2) {
        unsigned short* dst = (which == 0 ? out0 : out1) + (unsigned long long)b * 524288ull;
#pragma unroll
        for (int mi = 0; mi < 4; ++mi) {
          const int pbase = m0 + wm + mi * 16 + r0;
#pragma unroll
          for (int r = 0; r < 4; ++r)
            dst[(unsigned long long)(pbase + r) * 512ull + oin] = f2bf((acc[mi][ni][r] + bi) * scale);
        }
      } else {
        unsigned short* dst = out2 + (unsigned long long)b * 524288ull + (unsigned long long)oin * 1024ull;
#pragma unroll
        for (int mi = 0; mi < 4; ++mi) {
          const int pbase = m0 + wm + mi * 16 + r0;
          unsigned short h4[4] __attribute__((aligned(8)));
#pragma unroll
          for (int r = 0; r < 4; ++r) h4[r] = f2bf(acc[mi][ni][r] + bi);
          *(int2*)(dst + pbase) = *(int2*)h4;
        }
      }
    }
  } else if (MODE == 1) {
    // acc[mi][ni][r] = S^T: j = m0+wm+mi*16+quad*4+r (row), i = n0+wn+ni*16+lane&15 (col)
    // softmax chunk of 32 j = mi-pair x 4 regs x 4 quads. exp in place (no max
    // subtraction: |S| <= ~1.5, expf exact; softmax shift-invariant).
#pragma unroll
    for (int mi = 0; mi < 4; ++mi)
#pragma unroll
      for (int ni = 0; ni < 4; ++ni)
#pragma unroll
        for (int r = 0; r < 4; ++r) acc[mi][ni][r] = __expf(acc[mi][ni][r]);
    float inv[4][2];
#pragma unroll
    for (int ni = 0; ni < 4; ++ni)
#pragma unroll
      for (int cp = 0; cp < 2; ++cp) {
        float s8 = 0.f;
#pragma unroll
        for (int mm = 0; mm < 2; ++mm)
#pragma unroll
          for (int r = 0; r < 4; ++r) s8 += acc[cp * 2 + mm][ni][r];
        s8 += __shfl_xor(s8, 16);
        s8 += __shfl_xor(s8, 32);
        inv[ni][cp] = 1.f / s8;
      }
    // transpose through LDS (As/Bs dead): Pt[i][j], pitch 136 (16B-aligned rows)
    unsigned short* Pt = smem;
#pragma unroll
    for (int mi = 0; mi < 4; ++mi)
#pragma unroll
      for (int ni = 0; ni < 4; ++ni) {
        unsigned short p4[4] __attribute__((aligned(8)));
#pragma unroll
        for (int r = 0; r < 4; ++r) p4[r] = f2bf(acc[mi][ni][r] * inv[ni][mi >> 1]);
        const int li = wn + ni * 16 + cn;
        const int lj = wm + mi * 16 + r0;
        *(int2*)(Pt + li * 136 + lj) = *(int2*)p4;
      }
    __syncthreads();
    unsigned short* dst = out0 + (unsigned long long)b * 1048576ull;
#pragma unroll
    for (int pass = 0; pass < 8; ++pass) {
      const int row = pass * 16 + (tid >> 4);
      const int col = (tid & 15) * 8;
      int4 v = *(const int4*)(Pt + row * 136 + col);
      *(int4*)(dst + (unsigned long long)(n0 + row) * 1024ull + m0 + col) = v;
    }
  } else if (MODE == 2) {
    unsigned short* dst = out0 + (unsigned long long)b * 524288ull;
#pragma unroll
    for (int mi = 0; mi < 4; ++mi) {
      const int ib = m0 + wm + mi * 16 + r0;
#pragma unroll
      for (int ni = 0; ni < 4; ++ni) {
        const int c = n0 + wn + ni * 16 + cn;
#pragma unroll
        for (int r = 0; r < 4; ++r)
          dst[(unsigned long long)(ib + r) * 512ull + c] = f2bf(acc[mi][ni][r]);
      }
    }
  } else {  // MODE 3: fp32 out = acc + bias + x
    float* dst = fout + (unsigned long long)b * 524288ull;
    const float* xr = xres + (unsigned long long)b * 524288ull;
#pragma unroll
    for (int mi = 0; mi < 4; ++mi) {
      const int ob = m0 + wm + mi * 16 + r0;
#pragma unroll
      for (int r = 0; r < 4; ++r) {
        const int o = ob + r;
        const float bi = bias[o];
#pragma unroll
        for (int ni = 0; ni < 4; ++ni) {
          const int p = n0 + wn + ni * 16 + cn;
          const unsigned long long idx = (unsigned long long)o * 1024ull + p;
          dst[idx] = acc[mi][ni][r] + bi + xr[idx];
        }
      }
    }
  }
}

extern "C" void kernel_launch(void* const* d_in, const int* in_sizes, int n_in,
                              void* d_out, int out_size, void* d_ws, size_t ws_size,
                              hipStream_t stream) {
  const float* x     = (const float*)d_in[0];
  const float* gamma = (const float*)d_in[1];
  const float* beta  = (const float*)d_in[2];
  const float* qkvw  = (const float*)d_in[3];
  const float* qkvb  = (const float*)d_in[4];
  const float* projw = (const float*)d_in[5];
  const float* projb = (const float*)d_in[6];
  float* out = (float*)d_out;
  char* ws = (char*)d_ws;

  unsigned short* Hin = (unsigned short*)(ws);                        // 32 MB [b][p][c]
  unsigned short* Q   = (unsigned short*)(ws + 1ull * 33554432ull);   // 32 MB [b][p][c]
  unsigned short* Kb  = (unsigned short*)(ws + 2ull * 33554432ull);   // 32 MB [b][p][c]
  unsigned short* V   = (unsigned short*)(ws + 3ull * 33554432ull);   // 32 MB [b][c][p]
  unsigned short* S   = (unsigned short*)(ws + 4ull * 33554432ull);   // 64 MB P[b][i][j]
  unsigned short* Wq  = (unsigned short*)(ws + 6ull * 33554432ull);   // 1.5 MB
  unsigned short* Wp  = (unsigned short*)(ws + 6ull * 33554432ull + 2ull * 1048576ull);
  unsigned short* H   = Hin;  // reuse: Hin dead after QKV GEMM

  const float SCALE = 0.21022410381342864f;  // 512^-0.25
  dim3 blk(256);
  const float* nzf = nullptr;
  unsigned short* nzo = nullptr;
  float* nzfo = nullptr;

  hipLaunchKernelGGL(cvt_k, dim3(768), blk, 0, stream, qkvw, Wq, 196608);
  hipLaunchKernelGGL(cvt_k, dim3(256), blk, 0, stream, projw, Wp, 65536);
  hipLaunchKernelGGL(groupnorm_k, dim3(1024), blk, 0, stream, x, gamma, beta, Hin);
  hipLaunchKernelGGL((gemm_k<0>), dim3(12, 8, 32), blk, 0, stream,
                     Hin, 524288ull, 512, Wq, 0ull, 512, qkvb, nzf, Q, Kb, V, nzfo, SCALE, 512);
  // S^T: A = K (j rows), B = Q (i cols)
  hipLaunchKernelGGL((gemm_k<1>), dim3(8, 8, 32), blk, 0, stream,
                     Kb, 524288ull, 512, Q, 524288ull, 512, nzf, nzf, S, nzo, nzo, nzfo, 0.f, 512);
  hipLaunchKernelGGL((gemm_k<2>), dim3(4, 8, 32), blk, 0, stream,
                     S, 1048576ull, 1024, V, 524288ull, 1024, nzf, nzf, H, nzo, nzo, nzfo, 0.f, 1024);
  hipLaunchKernelGGL((gemm_k<3>), dim3(8, 4, 32), blk, 0, stream,
                     Wp, 0ull, 512, H, 524288ull, 512, projb, x, nzo, nzo, nzo, out, 0.f, 512);
}

// Round 6
// 350.196 us; speedup vs baseline: 1.2568x; 1.0720x over previous
//
#include <hip/hip_runtime.h>

typedef __attribute__((ext_vector_type(8))) short short8;
typedef __attribute__((ext_vector_type(4))) float f32x4;

__device__ __forceinline__ float b2f(unsigned short u) {
  union { unsigned u32; float f; } x; x.u32 = ((unsigned)u) << 16; return x.f;
}
__device__ __forceinline__ unsigned short f2bf(float f) {
  union { float f; unsigned u; } x; x.f = f;
  unsigned r = x.u + 0x7fffu + ((x.u >> 16) & 1u);
  return (unsigned short)(r >> 16);
}
__device__ __forceinline__ void async_load16(const void* g, void* l) {
  __builtin_amdgcn_global_load_lds(
      (__attribute__((address_space(1))) void*)(void*)(g),
      (__attribute__((address_space(3))) void*)(l), 16, 0, 0);
}

// ---- fp32 -> bf16 convert (weights), n4 = n/4 ----
__global__ __launch_bounds__(256) void cvt_k(const float* __restrict__ in,
                                             unsigned short* __restrict__ out, int n4) {
  int i = blockIdx.x * 256 + threadIdx.x;
  if (i < n4) {
    float4 v = ((const float4*)in)[i];
    unsigned short o[4] __attribute__((aligned(8)));
    o[0] = f2bf(v.x); o[1] = f2bf(v.y); o[2] = f2bf(v.z); o[3] = f2bf(v.w);
    ((int2*)out)[i] = *(int2*)o;
  }
}

// ---- GroupNorm single-pass: x[b][c][p] fp32 -> hin[b][p][c] bf16 (transposed) ----
__global__ __launch_bounds__(256) void groupnorm_k(
    const float* __restrict__ x, const float* __restrict__ gamma,
    const float* __restrict__ beta, unsigned short* __restrict__ hin) {
  const int b = blockIdx.x >> 5, g = blockIdx.x & 31;
  const float* xb = x + ((unsigned long long)b * 512ull + (unsigned long long)g * 16ull) * 1024ull;
  const int t = threadIdx.x;
  float4 xr[16];
  float s = 0.f, ss = 0.f;
#pragma unroll
  for (int c = 0; c < 16; ++c) {
    xr[c] = *(const float4*)(xb + c * 1024 + t * 4);
    s += xr[c].x + xr[c].y + xr[c].z + xr[c].w;
    ss += xr[c].x * xr[c].x + xr[c].y * xr[c].y + xr[c].z * xr[c].z + xr[c].w * xr[c].w;
  }
#pragma unroll
  for (int o = 32; o; o >>= 1) { s += __shfl_down(s, o); ss += __shfl_down(ss, o); }
  __shared__ float sred[8];
  if ((t & 63) == 0) { sred[t >> 6] = s; sred[4 + (t >> 6)] = ss; }
  __syncthreads();
  s = sred[0] + sred[1] + sred[2] + sred[3];
  ss = sred[4] + sred[5] + sred[6] + sred[7];
  const float mean = s * (1.f / 16384.f);
  const float rstd = rsqrtf(ss * (1.f / 16384.f) - mean * mean + 1e-5f);
  float ga[16], be[16];
#pragma unroll
  for (int c = 0; c < 16; ++c) {
    float gg = gamma[g * 16 + c] * rstd;
    ga[c] = gg;
    be[c] = beta[g * 16 + c] - mean * gg;
  }
#pragma unroll
  for (int p4 = 0; p4 < 4; ++p4) {
    unsigned short ov[16] __attribute__((aligned(16)));
#pragma unroll
    for (int c = 0; c < 16; ++c)
      ov[c] = f2bf(((const float*)&xr[c])[p4] * ga[c] + be[c]);
    unsigned short* dst = hin + ((unsigned long long)b * 1024ull + t * 4 + p4) * 512ull + g * 16;
    *(int4*)dst = *(int4*)ov;
    *(int4*)(dst + 8) = *(int4*)(ov + 8);
  }
}

// ---- GEMM: C[m][n] = sum_k A[m][k]*B[n][k], A/B bf16 K-contiguous ----
// MI = m-subtiles per wave (4 -> 128-row block, 8 -> 256-row block). N-tile 128.
// LDS XOR-swizzle on 16B col-blocks -> conflict-free ds_read_b128.
// MODE 0: QKV (MI=8). Epilogue: bias, scale q/k, V transposed [c][p]. XCD swizzle.
// MODE 1: S^T (MI=4, A=K, B=Q) + segmented softmax + LDS transpose -> P[i][j].
// MODE 2: PV (MI=8) -> H[b][i][c] bf16. XCD swizzle.
// MODE 3: proj (MI=8) -> fout = x + bias + acc (fp32)
template <int MODE, int MI>
__global__ __launch_bounds__(256, 2) void gemm_k(
    const unsigned short* __restrict__ A, unsigned long long sA, int lda,
    const unsigned short* __restrict__ B, unsigned long long sB, int ldb,
    const float* __restrict__ bias, const float* __restrict__ xres,
    unsigned short* __restrict__ out0, unsigned short* __restrict__ out1,
    unsigned short* __restrict__ out2, float* __restrict__ fout,
    float scale, int K) {
  constexpr int MBLK = MI * 32;  // block M size
  constexpr int SMEM_SHORTS = (MODE == 1) ? (128 * 136) : (MBLK * 32 + 4096);
  __shared__ unsigned short smem[SMEM_SHORTS];
  unsigned short* As = smem;
  unsigned short* Bs = smem + MBLK * 32;
  const int tid = threadIdx.x;
  const int wave = tid >> 6, lane = tid & 63;

  int n_t, m_t, b;
  if (MODE == 0) {
    // 1536 blocks; all 12 n-tiles of one (m,b) share L&7 -> same XCD A-tile reuse
    const int L = blockIdx.x + gridDim.x * (blockIdx.y + gridDim.y * blockIdx.z);
    const int r8 = L & 7, q = L >> 3;
    n_t = q % 12;
    const int mb = (q / 12) * 8 + r8;
    m_t = mb & 3;
    b = mb >> 2;
  } else if (MODE == 1) {
    const int L = blockIdx.x + gridDim.x * (blockIdx.y + gridDim.y * blockIdx.z);
    const int slice = L & 7, t = L >> 3;
    b = slice * 4 + (t >> 6);
    const int rem = t & 63;
    m_t = rem >> 3;
    n_t = rem & 7;
  } else if (MODE == 2) {
    // 512 blocks; slice owns 4 batches
    const int L = blockIdx.x + gridDim.x * (blockIdx.y + gridDim.y * blockIdx.z);
    const int slice = L & 7, t = L >> 3;
    b = slice * 4 + (t >> 4);
    const int rem = t & 15;
    m_t = rem >> 2;
    n_t = rem & 3;
  } else {
    n_t = blockIdx.x; m_t = blockIdx.y; b = blockIdx.z;
  }
  const int m0 = m_t * MBLK, n0 = n_t * 128;
  const int wm = (wave & 1) * (MI * 16), wn = (wave >> 1) * 64;
  const unsigned short* Ab = A + (unsigned long long)b * sA + (unsigned long long)m0 * lda;
  const unsigned short* Bb = B + (unsigned long long)b * sB + (unsigned long long)n0 * ldb;

  f32x4 acc[MI][4];
#pragma unroll
  for (int i = 0; i < MI; ++i)
#pragma unroll
    for (int j = 0; j < 4; ++j)
#pragma unroll
      for (int r = 0; r < 4; ++r) acc[i][j][r] = 0.f;

  const int lrow = lane & 15;
  const int lk = lane >> 4;
  const int srow = lane >> 2;
  const int scol = (((lane & 3) ^ ((lane >> 3) & 3)) << 3);
  const int swz = (lrow >> 1) & 3;

  for (int kt = 0; kt < K; kt += 32) {
    {
      const unsigned short* ga = Ab + kt + (unsigned long long)(wave * 16 + srow) * lda + scol;
#pragma unroll
      for (int c = 0; c < MI / 2; ++c)
        async_load16(ga + (unsigned long long)(c * 64) * lda, (void*)(As + (wave + 4 * c) * 512));
      const unsigned short* gb = Bb + kt + (unsigned long long)(wave * 16 + srow) * ldb + scol;
      async_load16(gb, (void*)(Bs + wave * 512));
      async_load16(gb + 64ull * (unsigned long long)ldb, (void*)(Bs + (wave + 4) * 512));
    }
    __syncthreads();
    short8 af[MI], bfr[4];
#pragma unroll
    for (int i = 0; i < MI; ++i)
      af[i] = *(const short8*)(As + (wm + i * 16 + lrow) * 32 + ((lk ^ swz) << 3));
#pragma unroll
    for (int i = 0; i < 4; ++i)
      bfr[i] = *(const short8*)(Bs + (wn + i * 16 + lrow) * 32 + ((lk ^ swz) << 3));
#pragma unroll
    for (int mi = 0; mi < MI; ++mi)
#pragma unroll
      for (int ni = 0; ni < 4; ++ni)
        acc[mi][ni] = __builtin_amdgcn_mfma_f32_16x16x32_bf16(af[mi], bfr[ni], acc[mi][ni], 0, 0, 0);
    __syncthreads();
  }

  const int r0 = lk * 4;  // C/D: row = (lane>>4)*4 + reg
  const int cn = lrow;    // C/D: col = lane&15

  if (MODE == 0) {
    const int which = n0 >> 9;  // 0=Q 1=K 2=V
#pragma unroll
    for (int ni = 0; ni < 4; ++ni) {
      const int o = n0 + wn + ni * 16 + cn;
      const float bi = bias[o];
      const int oin = o & 511;
      if (which < 2) {
        unsigned short* dst = (which == 0 ? out0 : out1) + (unsigned long long)b * 524288ull;
#pragma unroll
        for (int mi = 0; mi < MI; ++mi) {
          const int pbase = m0 + wm + mi * 16 + r0;
#pragma unroll
          for (int r = 0; r < 4; ++r)
            dst[(unsigned long long)(pbase + r) * 512ull + oin] = f2bf((acc[mi][ni][r] + bi) * scale);
        }
      } else {
        unsigned short* dst = out2 + (unsigned long long)b * 524288ull + (unsigned long long)oin * 1024ull;
#pragma unroll
        for (int mi = 0; mi < MI; ++mi) {
          const int pbase = m0 + wm + mi * 16 + r0;
          unsigned short h4[4] __attribute__((aligned(8)));
#pragma unroll
          for (int r = 0; r < 4; ++r) h4[r] = f2bf(acc[mi][ni][r] + bi);
          *(int2*)(dst + pbase) = *(int2*)h4;
        }
      }
    }
  } else if (MODE == 1) {
    // acc = S^T: j = m0+wm+mi*16+quad*4+r (row), i = n0+wn+ni*16+cn (col)
    // segmented softmax (32-j chunks = mi-pair x regs x quads); expf w/o max-sub
#pragma unroll
    for (int mi = 0; mi < MI; ++mi)
#pragma unroll
      for (int ni = 0; ni < 4; ++ni)
#pragma unroll
        for (int r = 0; r < 4; ++r) acc[mi][ni][r] = __expf(acc[mi][ni][r]);
    float inv[4][MI / 2];
#pragma unroll
    for (int ni = 0; ni < 4; ++ni)
#pragma unroll
      for (int cp = 0; cp < MI / 2; ++cp) {
        float s8 = 0.f;
#pragma unroll
        for (int mm = 0; mm < 2; ++mm)
#pragma unroll
          for (int r = 0; r < 4; ++r) s8 += acc[cp * 2 + mm][ni][r];
        s8 += __shfl_xor(s8, 16);
        s8 += __shfl_xor(s8, 32);
        inv[ni][cp] = 1.f / s8;
      }
    unsigned short* Pt = smem;
#pragma unroll
    for (int mi = 0; mi < MI; ++mi)
#pragma unroll
      for (int ni = 0; ni < 4; ++ni) {
        unsigned short p4[4] __attribute__((aligned(8)));
#pragma unroll
        for (int r = 0; r < 4; ++r) p4[r] = f2bf(acc[mi][ni][r] * inv[ni][mi >> 1]);
        const int li = wn + ni * 16 + cn;
        const int lj = wm + mi * 16 + r0;
        *(int2*)(Pt + li * 136 + lj) = *(int2*)p4;
      }
    __syncthreads();
    unsigned short* dst = out0 + (unsigned long long)b * 1048576ull;
#pragma unroll
    for (int pass = 0; pass < 8; ++pass) {
      const int row = pass * 16 + (tid >> 4);
      const int col = (tid & 15) * 8;
      int4 v = *(const int4*)(Pt + row * 136 + col);
      *(int4*)(dst + (unsigned long long)(n0 + row) * 1024ull + m0 + col) = v;
    }
  } else if (MODE == 2) {
    unsigned short* dst = out0 + (unsigned long long)b * 524288ull;
#pragma unroll
    for (int mi = 0; mi < MI; ++mi) {
      const int ib = m0 + wm + mi * 16 + r0;
#pragma unroll
      for (int ni = 0; ni < 4; ++ni) {
        const int c = n0 + wn + ni * 16 + cn;
#pragma unroll
        for (int r = 0; r < 4; ++r)
          dst[(unsigned long long)(ib + r) * 512ull + c] = f2bf(acc[mi][ni][r]);
      }
    }
  } else {  // MODE 3: fp32 out = acc + bias + x
    float* dst = fout + (unsigned long long)b * 524288ull;
    const float* xr = xres + (unsigned long long)b * 524288ull;
#pragma unroll
    for (int mi = 0; mi < MI; ++mi) {
      const int ob = m0 + wm + mi * 16 + r0;
#pragma unroll
      for (int r = 0; r < 4; ++r) {
        const int o = ob + r;
        const float bi = bias[o];
#pragma unroll
        for (int ni = 0; ni < 4; ++ni) {
          const int p = n0 + wn + ni * 16 + cn;
          const unsigned long long idx = (unsigned long long)o * 1024ull + p;
          dst[idx] = acc[mi][ni][r] + bi + xr[idx];
        }
      }
    }
  }
}

extern "C" void kernel_launch(void* const* d_in, const int* in_sizes, int n_in,
                              void* d_out, int out_size, void* d_ws, size_t ws_size,
                              hipStream_t stream) {
  const float* x     = (const float*)d_in[0];
  const float* gamma = (const float*)d_in[1];
  const float* beta  = (const float*)d_in[2];
  const float* qkvw  = (const float*)d_in[3];
  const float* qkvb  = (const float*)d_in[4];
  const float* projw = (const float*)d_in[5];
  const float* projb = (const float*)d_in[6];
  float* out = (float*)d_out;
  char* ws = (char*)d_ws;

  unsigned short* Hin = (unsigned short*)(ws);                        // 32 MB [b][p][c]
  unsigned short* Q   = (unsigned short*)(ws + 1ull * 33554432ull);   // 32 MB [b][p][c]
  unsigned short* Kb  = (unsigned short*)(ws + 2ull * 33554432ull);   // 32 MB [b][p][c]
  unsigned short* V   = (unsigned short*)(ws + 3ull * 33554432ull);   // 32 MB [b][c][p]
  unsigned short* S   = (unsigned short*)(ws + 4ull * 33554432ull);   // 64 MB P[b][i][j]
  unsigned short* Wq  = (unsigned short*)(ws + 6ull * 33554432ull);   // 1.5 MB
  unsigned short* Wp  = (unsigned short*)(ws + 6ull * 33554432ull + 2ull * 1048576ull);
  unsigned short* H   = Hin;  // reuse: Hin dead after QKV GEMM

  const float SCALE = 0.21022410381342864f;  // 512^-0.25
  dim3 blk(256);
  const float* nzf = nullptr;
  unsigned short* nzo = nullptr;
  float* nzfo = nullptr;

  hipLaunchKernelGGL(cvt_k, dim3(768), blk, 0, stream, qkvw, Wq, 196608);
  hipLaunchKernelGGL(cvt_k, dim3(256), blk, 0, stream, projw, Wp, 65536);
  hipLaunchKernelGGL(groupnorm_k, dim3(1024), blk, 0, stream, x, gamma, beta, Hin);
  hipLaunchKernelGGL((gemm_k<0, 8>), dim3(12, 4, 32), blk, 0, stream,
                     Hin, 524288ull, 512, Wq, 0ull, 512, qkvb, nzf, Q, Kb, V, nzfo, SCALE, 512);
  // S^T: A = K (j rows), B = Q (i cols)
  hipLaunchKernelGGL((gemm_k<1, 4>), dim3(8, 8, 32), blk, 0, stream,
                     Kb, 524288ull, 512, Q, 524288ull, 512, nzf, nzf, S, nzo, nzo, nzfo, 0.f, 512);
  hipLaunchKernelGGL((gemm_k<2, 8>), dim3(4, 4, 32), blk, 0, stream,
                     S, 1048576ull, 1024, V, 524288ull, 1024, nzf, nzf, H, nzo, nzo, nzfo, 0.f, 1024);
  hipLaunchKernelGGL((gemm_k<3, 8>), dim3(8, 2, 32), blk, 0, stream,
                     Wp, 0ull, 512, H, 524288ull, 512, projb, x, nzo, nzo, nzo, out, 0.f, 512);
}

// Round 7
// 321.009 us; speedup vs baseline: 1.3711x; 1.0909x over previous
//
#include <hip/hip_runtime.h>

typedef __attribute__((ext_vector_type(8))) short short8;
typedef __attribute__((ext_vector_type(4))) float f32x4;

__device__ __forceinline__ float b2f(unsigned short u) {
  union { unsigned u32; float f; } x; x.u32 = ((unsigned)u) << 16; return x.f;
}
__device__ __forceinline__ unsigned short f2bf(float f) {
  union { float f; unsigned u; } x; x.f = f;
  unsigned r = x.u + 0x7fffu + ((x.u >> 16) & 1u);
  return (unsigned short)(r >> 16);
}
__device__ __forceinline__ void async_load16(const void* g, void* l) {
  __builtin_amdgcn_global_load_lds(
      (__attribute__((address_space(1))) void*)(void*)(g),
      (__attribute__((address_space(3))) void*)(l), 16, 0, 0);
}

// ---- fp32 -> bf16 convert of both weight arrays, one dispatch ----
__global__ __launch_bounds__(256) void cvt2_k(
    const float* __restrict__ a, unsigned short* __restrict__ oa, int n4a,
    const float* __restrict__ bsrc, unsigned short* __restrict__ ob, int n4b) {
  int i = blockIdx.x * 256 + threadIdx.x;
  const float* src; unsigned short* dst; int idx;
  if (i < n4a) { src = a; dst = oa; idx = i; }
  else if (i < n4a + n4b) { src = bsrc; dst = ob; idx = i - n4a; }
  else return;
  float4 v = ((const float4*)src)[idx];
  unsigned short o[4] __attribute__((aligned(8)));
  o[0] = f2bf(v.x); o[1] = f2bf(v.y); o[2] = f2bf(v.z); o[3] = f2bf(v.w);
  ((int2*)dst)[idx] = *(int2*)o;
}

// ---- GroupNorm single-pass: x[b][c][p] fp32 -> hin[b][p][c] bf16 (transposed) ----
__global__ __launch_bounds__(256) void groupnorm_k(
    const float* __restrict__ x, const float* __restrict__ gamma,
    const float* __restrict__ beta, unsigned short* __restrict__ hin) {
  const int b = blockIdx.x >> 5, g = blockIdx.x & 31;
  const float* xb = x + ((unsigned long long)b * 512ull + (unsigned long long)g * 16ull) * 1024ull;
  const int t = threadIdx.x;
  float4 xr[16];
  float s = 0.f, ss = 0.f;
#pragma unroll
  for (int c = 0; c < 16; ++c) {
    xr[c] = *(const float4*)(xb + c * 1024 + t * 4);
    s += xr[c].x + xr[c].y + xr[c].z + xr[c].w;
    ss += xr[c].x * xr[c].x + xr[c].y * xr[c].y + xr[c].z * xr[c].z + xr[c].w * xr[c].w;
  }
#pragma unroll
  for (int o = 32; o; o >>= 1) { s += __shfl_down(s, o); ss += __shfl_down(ss, o); }
  __shared__ float sred[8];
  if ((t & 63) == 0) { sred[t >> 6] = s; sred[4 + (t >> 6)] = ss; }
  __syncthreads();
  s = sred[0] + sred[1] + sred[2] + sred[3];
  ss = sred[4] + sred[5] + sred[6] + sred[7];
  const float mean = s * (1.f / 16384.f);
  const float rstd = rsqrtf(ss * (1.f / 16384.f) - mean * mean + 1e-5f);
  float ga[16], be[16];
#pragma unroll
  for (int c = 0; c < 16; ++c) {
    float gg = gamma[g * 16 + c] * rstd;
    ga[c] = gg;
    be[c] = beta[g * 16 + c] - mean * gg;
  }
#pragma unroll
  for (int p4 = 0; p4 < 4; ++p4) {
    unsigned short ov[16] __attribute__((aligned(16)));
#pragma unroll
    for (int c = 0; c < 16; ++c)
      ov[c] = f2bf(((const float*)&xr[c])[p4] * ga[c] + be[c]);
    unsigned short* dst = hin + ((unsigned long long)b * 1024ull + t * 4 + p4) * 512ull + g * 16;
    *(int4*)dst = *(int4*)ov;
    *(int4*)(dst + 8) = *(int4*)(ov + 8);
  }
}

// ---- GEMM: C[m][n] = sum_k A[m][k]*B[n][k], A/B bf16 K-contiguous, BK=64 ----
// Staging rows are 128 B (64 ch); XOR swizzle kb^(row&7) applied to GLOBAL source
// columns (per-lane global addr ok; LDS dest is lane-fixed). Readers un-XOR.
// MODE 0: QKV (MI=8). Epilogue: bias, scale q/k, V transposed [c][p]. XCD swizzle.
// MODE 1: S^T (MI=4, A=K, B=Q) + segmented softmax + LDS transpose -> P[i][j].
// MODE 2: PV (MI=8) -> H[b][i][c] bf16. XCD swizzle.
// MODE 3: proj (MI=8) -> fout = x + bias + acc (fp32)
template <int MODE, int MI>
__global__ __launch_bounds__(256, 2) void gemm_k(
    const unsigned short* __restrict__ A, unsigned long long sA, int lda,
    const unsigned short* __restrict__ B, unsigned long long sB, int ldb,
    const float* __restrict__ bias, const float* __restrict__ xres,
    unsigned short* __restrict__ out0, unsigned short* __restrict__ out1,
    unsigned short* __restrict__ out2, float* __restrict__ fout,
    float scale, int K) {
  constexpr int MBLK = MI * 32;  // block M size
  constexpr int STAGE_SHORTS = MBLK * 64 + 128 * 64;
  constexpr int SMEM_SHORTS = (MODE == 1)
      ? ((STAGE_SHORTS > 128 * 136) ? STAGE_SHORTS : 128 * 136)
      : STAGE_SHORTS;
  __shared__ unsigned short smem[SMEM_SHORTS];
  unsigned short* As = smem;
  unsigned short* Bs = smem + MBLK * 64;
  const int tid = threadIdx.x;
  const int wave = tid >> 6, lane = tid & 63;

  int n_t, m_t, b;
  if (MODE == 0) {
    // 1536 blocks; all 12 n-tiles of one (m,b) share L&7 -> same XCD A-tile reuse
    const int L = blockIdx.x + gridDim.x * (blockIdx.y + gridDim.y * blockIdx.z);
    const int r8 = L & 7, q = L >> 3;
    n_t = q % 12;
    const int mb = (q / 12) * 8 + r8;
    m_t = mb & 3;
    b = mb >> 2;
  } else if (MODE == 1) {
    const int L = blockIdx.x + gridDim.x * (blockIdx.y + gridDim.y * blockIdx.z);
    const int slice = L & 7, t = L >> 3;
    b = slice * 4 + (t >> 6);
    const int rem = t & 63;
    m_t = rem >> 3;
    n_t = rem & 7;
  } else if (MODE == 2) {
    const int L = blockIdx.x + gridDim.x * (blockIdx.y + gridDim.y * blockIdx.z);
    const int slice = L & 7, t = L >> 3;
    b = slice * 4 + (t >> 4);
    const int rem = t & 15;
    m_t = rem >> 2;
    n_t = rem & 3;
  } else {
    n_t = blockIdx.x; m_t = blockIdx.y; b = blockIdx.z;
  }
  const int m0 = m_t * MBLK, n0 = n_t * 128;
  const int wm = (wave & 1) * (MI * 16), wn = (wave >> 1) * 64;
  const unsigned short* Ab = A + (unsigned long long)b * sA + (unsigned long long)m0 * lda;
  const unsigned short* Bb = B + (unsigned long long)b * sB + (unsigned long long)n0 * ldb;

  f32x4 acc[MI][4];
#pragma unroll
  for (int i = 0; i < MI; ++i)
#pragma unroll
    for (int j = 0; j < 4; ++j)
#pragma unroll
      for (int r = 0; r < 4; ++r) acc[i][j][r] = 0.f;

  const int lrow = lane & 15;
  const int lk = lane >> 4;
  const int sr = lane >> 3;                      // staging row within 8-row chunk
  const int pc = (((lane & 7) ^ sr) << 3);       // permuted global col (elements)
  const int r7 = lrow & 7;                       // reader row&7 (wm,16*i are mult of 8)

  for (int kt = 0; kt < K; kt += 64) {
    {
#pragma unroll
      for (int c = 0; c < MBLK / 32; ++c) {
        const int row = wave * (MBLK / 4) + c * 8;
        async_load16(Ab + kt + (unsigned long long)(row + sr) * lda + pc,
                     (void*)(As + row * 64));
      }
#pragma unroll
      for (int c = 0; c < 4; ++c) {
        const int row = wave * 32 + c * 8;
        async_load16(Bb + kt + (unsigned long long)(row + sr) * ldb + pc,
                     (void*)(Bs + row * 64));
      }
    }
    __syncthreads();
#pragma unroll
    for (int ks = 0; ks < 2; ++ks) {
      const int ko = (((ks << 2) + lk) ^ r7) << 3;
      short8 af[MI], bfr[4];
#pragma unroll
      for (int i = 0; i < MI; ++i)
        af[i] = *(const short8*)(As + (wm + i * 16 + lrow) * 64 + ko);
#pragma unroll
      for (int i = 0; i < 4; ++i)
        bfr[i] = *(const short8*)(Bs + (wn + i * 16 + lrow) * 64 + ko);
#pragma unroll
      for (int mi = 0; mi < MI; ++mi)
#pragma unroll
        for (int ni = 0; ni < 4; ++ni)
          acc[mi][ni] = __builtin_amdgcn_mfma_f32_16x16x32_bf16(af[mi], bfr[ni], acc[mi][ni], 0, 0, 0);
    }
    __syncthreads();
  }

  const int r0 = lk * 4;  // C/D: row = (lane>>4)*4 + reg
  const int cn = lrow;    // C/D: col = lane&15

  if (MODE == 0) {
    const int which = n0 >> 9;  // 0=Q 1=K 2=V
#pragma unroll
    for (int ni = 0; ni < 4; ++ni) {
      const int o = n0 + wn + ni * 16 + cn;
      const float bi = bias[o];
      const int oin = o & 511;
      if (which < 2) {
        unsigned short* dst = (which == 0 ? out0 : out1) + (unsigned long long)b * 524288ull;
#pragma unroll
        for (int mi = 0; mi < MI; ++mi) {
          const int pbase = m0 + wm + mi * 16 + r0;
#pragma unroll
          for (int r = 0; r < 4; ++r)
            dst[(unsigned long long)(pbase + r) * 512ull + oin] = f2bf((acc[mi][ni][r] + bi) * scale);
        }
      } else {
        unsigned short* dst = out2 + (unsigned long long)b * 524288ull + (unsigned long long)oin * 1024ull;
#pragma unroll
        for (int mi = 0; mi < MI; ++mi) {
          const int pbase = m0 + wm + mi * 16 + r0;
          unsigned short h4[4] __attribute__((aligned(8)));
#pragma unroll
          for (int r = 0; r < 4; ++r) h4[r] = f2bf(acc[mi][ni][r] + bi);
          *(int2*)(dst + pbase) = *(int2*)h4;
        }
      }
    }
  } else if (MODE == 1) {
    // acc = S^T: j = m0+wm+mi*16+quad*4+r (row), i = n0+wn+ni*16+cn (col)
#pragma unroll
    for (int mi = 0; mi < MI; ++mi)
#pragma unroll
      for (int ni = 0; ni < 4; ++ni)
#pragma unroll
        for (int r = 0; r < 4; ++r) acc[mi][ni][r] = __expf(acc[mi][ni][r]);
    float inv[4][MI / 2];
#pragma unroll
    for (int ni = 0; ni < 4; ++ni)
#pragma unroll
      for (int cp = 0; cp < MI / 2; ++cp) {
        float s8 = 0.f;
#pragma unroll
        for (int mm = 0; mm < 2; ++mm)
#pragma unroll
          for (int r = 0; r < 4; ++r) s8 += acc[cp * 2 + mm][ni][r];
        s8 += __shfl_xor(s8, 16);
        s8 += __shfl_xor(s8, 32);
        inv[ni][cp] = 1.f / s8;
      }
    unsigned short* Pt = smem;
#pragma unroll
    for (int mi = 0; mi < MI; ++mi)
#pragma unroll
      for (int ni = 0; ni < 4; ++ni) {
        unsigned short p4[4] __attribute__((aligned(8)));
#pragma unroll
        for (int r = 0; r < 4; ++r) p4[r] = f2bf(acc[mi][ni][r] * inv[ni][mi >> 1]);
        const int li = wn + ni * 16 + cn;
        const int lj = wm + mi * 16 + r0;
        *(int2*)(Pt + li * 136 + lj) = *(int2*)p4;
      }
    __syncthreads();
    unsigned short* dst = out0 + (unsigned long long)b * 1048576ull;
#pragma unroll
    for (int pass = 0; pass < 8; ++pass) {
      const int row = pass * 16 + (tid >> 4);
      const int col = (tid & 15) * 8;
      int4 v = *(const int4*)(Pt + row * 136 + col);
      *(int4*)(dst + (unsigned long long)(n0 + row) * 1024ull + m0 + col) = v;
    }
  } else if (MODE == 2) {
    unsigned short* dst = out0 + (unsigned long long)b * 524288ull;
#pragma unroll
    for (int mi = 0; mi < MI; ++mi) {
      const int ib = m0 + wm + mi * 16 + r0;
#pragma unroll
      for (int ni = 0; ni < 4; ++ni) {
        const int c = n0 + wn + ni * 16 + cn;
#pragma unroll
        for (int r = 0; r < 4; ++r)
          dst[(unsigned long long)(ib + r) * 512ull + c] = f2bf(acc[mi][ni][r]);
      }
    }
  } else {  // MODE 3: fp32 out = acc + bias + x
    float* dst = fout + (unsigned long long)b * 524288ull;
    const float* xr = xres + (unsigned long long)b * 524288ull;
#pragma unroll
    for (int mi = 0; mi < MI; ++mi) {
      const int ob = m0 + wm + mi * 16 + r0;
#pragma unroll
      for (int r = 0; r < 4; ++r) {
        const int o = ob + r;
        const float bi = bias[o];
#pragma unroll
        for (int ni = 0; ni < 4; ++ni) {
          const int p = n0 + wn + ni * 16 + cn;
          const unsigned long long idx = (unsigned long long)o * 1024ull + p;
          dst[idx] = acc[mi][ni][r] + bi + xr[idx];
        }
      }
    }
  }
}

extern "C" void kernel_launch(void* const* d_in, const int* in_sizes, int n_in,
                              void* d_out, int out_size, void* d_ws, size_t ws_size,
                              hipStream_t stream) {
  const float* x     = (const float*)d_in[0];
  const float* gamma = (const float*)d_in[1];
  const float* beta  = (const float*)d_in[2];
  const float* qkvw  = (const float*)d_in[3];
  const float* qkvb  = (const float*)d_in[4];
  const float* projw = (const float*)d_in[5];
  const float* projb = (const float*)d_in[6];
  float* out = (float*)d_out;
  char* ws = (char*)d_ws;

  unsigned short* Hin = (unsigned short*)(ws);                        // 32 MB [b][p][c]
  unsigned short* Q   = (unsigned short*)(ws + 1ull * 33554432ull);   // 32 MB [b][p][c]
  unsigned short* Kb  = (unsigned short*)(ws + 2ull * 33554432ull);   // 32 MB [b][p][c]
  unsigned short* V   = (unsigned short*)(ws + 3ull * 33554432ull);   // 32 MB [b][c][p]
  unsigned short* S   = (unsigned short*)(ws + 4ull * 33554432ull);   // 64 MB P[b][i][j]
  unsigned short* Wq  = (unsigned short*)(ws + 6ull * 33554432ull);   // 1.5 MB
  unsigned short* Wp  = (unsigned short*)(ws + 6ull * 33554432ull + 2ull * 1048576ull);
  unsigned short* H   = Hin;  // reuse: Hin dead after QKV GEMM

  const float SCALE = 0.21022410381342864f;  // 512^-0.25
  dim3 blk(256);
  const float* nzf = nullptr;
  unsigned short* nzo = nullptr;
  float* nzfo = nullptr;

  hipLaunchKernelGGL(cvt2_k, dim3(1024), blk, 0, stream, qkvw, Wq, 196608, projw, Wp, 65536);
  hipLaunchKernelGGL(groupnorm_k, dim3(1024), blk, 0, stream, x, gamma, beta, Hin);
  hipLaunchKernelGGL((gemm_k<0, 8>), dim3(12, 4, 32), blk, 0, stream,
                     Hin, 524288ull, 512, Wq, 0ull, 512, qkvb, nzf, Q, Kb, V, nzfo, SCALE, 512);
  // S^T: A = K (j rows), B = Q (i cols)
  hipLaunchKernelGGL((gemm_k<1, 4>), dim3(8, 8, 32), blk, 0, stream,
                     Kb, 524288ull, 512, Q, 524288ull, 512, nzf, nzf, S, nzo, nzo, nzfo, 0.f, 512);
  hipLaunchKernelGGL((gemm_k<2, 8>), dim3(4, 4, 32), blk, 0, stream,
                     S, 1048576ull, 1024, V, 524288ull, 1024, nzf, nzf, H, nzo, nzo, nzfo, 0.f, 1024);
  hipLaunchKernelGGL((gemm_k<3, 8>), dim3(8, 2, 32), blk, 0, stream,
                     Wp, 0ull, 512, H, 524288ull, 512, projb, x, nzo, nzo, nzo, out, 0.f, 512);
}